// Round 8
// baseline (2457.348 us; speedup 1.0000x reference)
//
#include <hip/hip_runtime.h>

#define T_STEPS 1024
#define BATCH   256
#define IND     128
#define HID     256
#define OUTD    64

typedef float  f32x4  __attribute__((ext_vector_type(4)));
typedef __bf16 bf16x8 __attribute__((ext_vector_type(8)));
typedef long   lx2    __attribute__((ext_vector_type(2)));

__device__ __forceinline__ bf16x8 cvt8(float4 a, float4 b){
  bf16x8 v;
  v[0]=(__bf16)a.x; v[1]=(__bf16)a.y; v[2]=(__bf16)a.z; v[3]=(__bf16)a.w;
  v[4]=(__bf16)b.x; v[5]=(__bf16)b.y; v[6]=(__bf16)b.z; v[7]=(__bf16)b.w;
  return v;
}
__device__ __forceinline__ int pk_fp8x4(float a, float b, float c, float d){
  int r = __builtin_amdgcn_cvt_pk_fp8_f32(a, b, 0, false);
  r     = __builtin_amdgcn_cvt_pk_fp8_f32(c, d, r, true);
  return r;
}
__device__ __forceinline__ float bflo(unsigned u){ return __builtin_bit_cast(float, u<<16); }
__device__ __forceinline__ float bfhi(unsigned u){ return __builtin_bit_cast(float, u & 0xffff0000u); }

// uxz h-permutation (this round): h = {b7:6=wl, b5:4=nt, b3:2=kg, b1:0=j}
//  -> ph = {b7:6=wl, b5:4=kg, b3:2=nt, b1:0=j}; scan lane owns 16 CONTIGUOUS
//  elements (32B) at ph = wl*64 + kg*16.

// ---------------------------------------------------------------------------
// Kernel 1: uxz'[t,b,ph] = bf16( 3.2*(x@U^T + b_U + b_real) )
// ---------------------------------------------------------------------------
__global__ __launch_bounds__(256) void ux_gemm(const float* __restrict__ x,
                                               const float* __restrict__ U,
                                               const float* __restrict__ b_real,
                                               const float* __restrict__ b_U,
                                               __bf16* __restrict__ uxz){
  __shared__ bf16x8 Ub[4096];   // [16 nt][4 c][64 lanes] A-frags, 64 KB
  const int tid = threadIdx.x;
  for(int s = tid; s < 4096; s += 256){
    const int l = s & 63, c = (s>>6)&3, nt = s>>8;
    const int n = nt*16 + (l&15), k = c*32 + ((l>>4)<<3);
    const float4* p = (const float4*)(U + n*IND + k);
    Ub[s] = cvt8(p[0], p[1]);
  }
  __syncthreads();
  const int wave = tid>>6, lane = tid&63, ln15 = lane&15, kg = lane>>4;
  const int row0 = blockIdx.x*64 + wave*16;
  const int grow = row0 + ln15;
  bf16x8 xf[4];
  #pragma unroll
  for(int c=0;c<4;c++){
    const float4* p = (const float4*)(x + (size_t)grow*IND + c*32 + (kg<<3));
    xf[c] = cvt8(p[0], p[1]);
  }
  #pragma unroll
  for(int nt=0;nt<16;nt++){
    f32x4 acc = {0.f,0.f,0.f,0.f};
    #pragma unroll
    for(int c=0;c<4;c++)
      acc = __builtin_amdgcn_mfma_f32_16x16x32_bf16(Ub[(nt*4+c)*64 + lane], xf[c], acc, 0,0,0);
    const int hb = nt*16 + (kg<<2);
    const float4 br = *(const float4*)(b_real + hb);
    const float4 bu = *(const float4*)(b_U + hb);
    const float brv[4] = {br.x,br.y,br.z,br.w};
    const float buv[4] = {bu.x,bu.y,bu.z,bu.w};
    unsigned short hs[4];
    #pragma unroll
    for(int j=0;j<4;j++)
      hs[j] = __builtin_bit_cast(unsigned short, (__bf16)(3.2f*(acc[j] + brv[j] + buv[j])));
    uint2 pk;
    pk.x = (unsigned)hs[0] | ((unsigned)hs[1]<<16);
    pk.y = (unsigned)hs[2] | ((unsigned)hs[3]<<16);
    // ph of (h=nt*16+kg*4+j): ((nt>>2)<<6) | (kg<<4) | ((nt&3)<<2) | j
    *(uint2*)(uxz + (size_t)grow*HID + ((nt>>2)<<6) + (kg<<4) + ((nt&3)<<2)) = pk;
  }
}

// ---------------------------------------------------------------------------
// Kernel 2: staggered dual-recurrence scan. 8 WGs x 512 thr (2 waves/SIMD).
// Group g = wave>>2 owns 16 batch rows; groups are HALF A STEP out of phase:
// per barrier slot, one group runs GEMM (MFMA+LDS) while the other runs
// elementwise (VALU+trans) -> pipes overlap on every SIMD (round-robin
// wave->SIMD puts one wave of each group per SIMD).
// Per-group SINGLE-buffered LDS state (z8 4KB + t8 4KB); all cross-wave
// traffic is LDS, so barriers are lgkm-only (no vmcnt drain) -> global
// prefetch/stores stay in flight across slots.
// ---------------------------------------------------------------------------
__global__ __launch_bounds__(512,2) void scan_k(
    const float* __restrict__ W_real, const float* __restrict__ W_tau,
    const float* __restrict__ b_tau,  __bf16* __restrict__ uxz){
  __shared__ char lds[16384];   // 2 groups x (z8 4KB + t8 4KB)
  const int tid = threadIdx.x, w = tid>>6, lane = tid&63;
  const int g = w>>2, wl = w&3;
  const int ln15 = lane&15, kg = lane>>4;
  const float KNEG = -0.09016844f;           // -log2(e)/16
  const float TL2E = 2.88539008f;            // 2*log2(e)

  // weights: wave wl owns h rows [wl*64, wl*64+64) (4 nt tiles)
  long wr8[4][8], wt8[4][8];
  #pragma unroll
  for(int nt=0;nt<4;nt++){
    const int n = wl*64 + nt*16 + ln15;
    #pragma unroll
    for(int c=0;c<8;c++){
      const int k = c*32 + (kg<<3);
      const float4 r0 = *(const float4*)(W_real + n*HID + k);
      const float4 r1 = *(const float4*)(W_real + n*HID + k + 4);
      const unsigned rlo = (unsigned)pk_fp8x4(3.2f*r0.x,3.2f*r0.y,3.2f*r0.z,3.2f*r0.w);
      const unsigned rhi = (unsigned)pk_fp8x4(3.2f*r1.x,3.2f*r1.y,3.2f*r1.z,3.2f*r1.w);
      wr8[nt][c] = (long)(((unsigned long)rhi<<32) | rlo);
      const float4 t0 = *(const float4*)(W_tau + n*HID + k);
      const float4 t1 = *(const float4*)(W_tau + n*HID + k + 4);
      const unsigned tlo = (unsigned)pk_fp8x4(16.f*t0.x,16.f*t0.y,16.f*t0.z,16.f*t0.w);
      const unsigned thi = (unsigned)pk_fp8x4(16.f*t1.x,16.f*t1.y,16.f*t1.z,16.f*t1.w);
      wt8[nt][c] = (long)(((unsigned long)thi<<32) | tlo);
    }
  }
  f32x4 bt16[4];
  #pragma unroll
  for(int nt=0;nt<4;nt++){
    const float4 bt = *(const float4*)(b_tau + wl*64 + nt*16 + (kg<<2));
    bt16[nt] = (f32x4){16.f*bt.x, 16.f*bt.y, 16.f*bt.z, 16.f*bt.w};
  }

  for(int s = tid; s < 1024; s += 512)
    ((float4*)lds)[s] = float4{0.f,0.f,0.f,0.f};
  __syncthreads();

  const int gb = g<<13;                              // group LDS base
  const int rb = gb + (lane<<4);                     // linear b128 read base
  // producer b32 write base; nt offsets = {0,512,8,520} (+4096 for tanh)
  const int vb = gb + (wl<<10) + ((kg>>1)<<8) + (ln15<<4) + ((kg&1)<<2);
  #define ZOFF(nt) ((((nt)&1)<<9) + (((nt)>>1)<<3))

  const int row  = blockIdx.x*32 + g*16 + ln15;
  const int loff = row*HID + (wl<<6) + (kg<<4);      // lane's 16-elem slot

  float zr[4][4];
  #pragma unroll
  for(int nt=0;nt<4;nt++)
    #pragma unroll
    for(int j=0;j<4;j++) zr[nt][j]=0.f;

  uint4 uxr0 = *(const uint4*)(uxz + loff);
  uint4 uxr1 = *(const uint4*)(uxz + loff + 8);
  const __bf16* pn1 = uxz + (size_t)(BATCH*HID) + loff;
  uint4 uxn0 = *(const uint4*)(pn1);
  uint4 uxn1 = *(const uint4*)(pn1 + 8);

  f32x4 aT[4], aR[4];

  auto GEMM = [&](){
    const unsigned dw[8] = {uxr0.x,uxr0.y,uxr0.z,uxr0.w, uxr1.x,uxr1.y,uxr1.z,uxr1.w};
    #pragma unroll
    for(int nt=0;nt<4;nt++){
      aT[nt] = bt16[nt];
      aR[nt] = (f32x4){bflo(dw[2*nt]), bfhi(dw[2*nt]), bflo(dw[2*nt+1]), bfhi(dw[2*nt+1])};
    }
    #pragma unroll
    for(int p=0;p<4;p++){
      const lx2 z2 = *(const lx2*)(lds + rb + p*1024);
      const lx2 t2 = *(const lx2*)(lds + rb + 4096 + p*1024);
      #pragma unroll
      for(int nt=0;nt<4;nt++){
        aT[nt] = __builtin_amdgcn_mfma_f32_16x16x32_fp8_fp8(wt8[nt][2*p],   z2.x, aT[nt], 0,0,0);
        aT[nt] = __builtin_amdgcn_mfma_f32_16x16x32_fp8_fp8(wt8[nt][2*p+1], z2.y, aT[nt], 0,0,0);
        aR[nt] = __builtin_amdgcn_mfma_f32_16x16x32_fp8_fp8(wr8[nt][2*p],   t2.x, aR[nt], 0,0,0);
        aR[nt] = __builtin_amdgcn_mfma_f32_16x16x32_fp8_fp8(wr8[nt][2*p+1], t2.y, aR[nt], 0,0,0);
      }
    }
  };

  auto EW = [&](int t){
    uxr0 = uxn0; uxr1 = uxn1;                    // ux(t+1), issued 2 slots ago
    int tn = t + 2; if(tn > T_STEPS-1) tn = T_STEPS-1;
    const __bf16* pn = uxz + (size_t)tn*(BATCH*HID) + loff;
    uxn0 = *(const uint4*)(pn);
    uxn1 = *(const uint4*)(pn + 8);
    uint4 zs0, zs1;
    #pragma unroll
    for(int nt=0;nt<4;nt++){
      float znv[4], tvv[4];
      unsigned short zh[4];
      #pragma unroll
      for(int j=0;j<4;j++){
        const float gg = __builtin_amdgcn_exp2f(aT[nt][j]*KNEG);      // e^{-x}
        const float d  = __builtin_fmaf(aR[nt][j], 0.03125f, -0.1f*zr[nt][j]);
        const float s  = zr[nt][j] + d;
        const float zn = __builtin_fmaf(d, gg, s);                    // zr+0.1pre(1+g)
        zr[nt][j] = zn;
        znv[j] = zn;
        const float e2 = __builtin_amdgcn_exp2f(zn*TL2E);
        const float r  = __builtin_amdgcn_rcpf(e2 + 1.f);
        tvv[j] = __builtin_fmaf(-2.f, r, 1.f);                        // tanh(zn)
        zh[j]  = __builtin_bit_cast(unsigned short, (__bf16)zn);
      }
      const int z8v = pk_fp8x4(znv[0],znv[1],znv[2],znv[3]);
      const int t8v = pk_fp8x4(tvv[0],tvv[1],tvv[2],tvv[3]);
      *(int*)(lds + vb + ZOFF(nt))        = z8v;
      *(int*)(lds + vb + 4096 + ZOFF(nt)) = t8v;
      const unsigned lo = (unsigned)zh[0] | ((unsigned)zh[1]<<16);
      const unsigned hi = (unsigned)zh[2] | ((unsigned)zh[3]<<16);
      if(nt==0){ zs0.x=lo; zs0.y=hi; } else if(nt==1){ zs0.z=lo; zs0.w=hi; }
      else if(nt==2){ zs1.x=lo; zs1.y=hi; } else { zs1.z=lo; zs1.w=hi; }
    }
    __bf16* ps = uxz + (size_t)t*(BATCH*HID) + loff;  // zr_t for y_gemm
    *(uint4*)(ps)     = zs0;
    *(uint4*)(ps + 8) = zs1;
  };

  for(int slot = 0; slot < 2*T_STEPS+1; ++slot){
    const int ph = slot - g;                     // G1 runs half a step behind
    if(ph >= 0 && ph < 2*T_STEPS){
      if((ph & 1) == 0) GEMM();
      else              EW(ph >> 1);
    }
    asm volatile("s_waitcnt lgkmcnt(0)" ::: "memory");  // LDS writes visible
    __builtin_amdgcn_s_barrier();                       // no vmcnt drain
    asm volatile("" ::: "memory");
  }
  #undef ZOFF
}

// ---------------------------------------------------------------------------
// Kernel 3: y[m,o] = sum_h zr[m,h] * W_out[o,h] + b_out[o]   (fp32 out)
// zr read from the permuted uxz layout (2xb64 per 32-wide k-chunk).
// ---------------------------------------------------------------------------
__global__ __launch_bounds__(256) void y_gemm(
    const __bf16* __restrict__ zrbuf, const float* __restrict__ W_out,
    const float* __restrict__ b_out, float* __restrict__ y){
  __shared__ bf16x8 Wo[2048];   // [4 nt][8 c][64 lanes], 32 KB
  const int tid = threadIdx.x;
  for(int s=tid; s<2048; s+=256){
    const int l = s&63, c = (s>>6)&7, nt = s>>9;
    const int n = nt*16 + (l&15), k = c*32 + ((l>>4)<<3);
    const float4* p = (const float4*)(W_out + n*HID + k);
    Wo[s] = cvt8(p[0], p[1]);
  }
  __syncthreads();
  const int wave = tid>>6, lane = tid&63, kg = lane>>4;
  const int row0 = blockIdx.x*64 + wave*16;
  const __bf16* zb = zrbuf + (size_t)(row0 + (lane&15))*HID;
  bf16x8 af[8];
  #pragma unroll
  for(int c=0;c<8;c++){
    // k = c*32 + kg*8 + e  ->  ph pieces: e<4 at pA, e>=4 at pA+16
    const int pA = ((c>>1)<<6) + ((kg&1)<<5) + ((c&1)<<3) + ((kg>>1)<<2);
    const uint2 lo = *(const uint2*)(zb + pA);
    const uint2 hi = *(const uint2*)(zb + pA + 16);
    af[c] = __builtin_bit_cast(bf16x8, (uint4){lo.x, lo.y, hi.x, hi.y});
  }
  f32x4 acc[4];
  #pragma unroll
  for(int nt=0;nt<4;nt++) acc[nt] = (f32x4){0,0,0,0};
  #pragma unroll
  for(int nt=0;nt<4;nt++)
    #pragma unroll
    for(int c=0;c<8;c++)
      acc[nt] = __builtin_amdgcn_mfma_f32_16x16x32_bf16(af[c], Wo[(nt*8+c)*64 + lane], acc[nt], 0,0,0);
  const int mb = (lane>>4)<<2, oc = lane&15;
  #pragma unroll
  for(int nt=0;nt<4;nt++){
    const float bo = b_out[nt*16 + oc];
    #pragma unroll
    for(int j=0;j<4;j++)
      y[(size_t)(row0 + mb + j)*OUTD + nt*16 + oc] = acc[nt][j] + bo;
  }
}

extern "C" void kernel_launch(void* const* d_in, const int* in_sizes, int n_in,
                              void* d_out, int out_size, void* d_ws, size_t ws_size,
                              hipStream_t stream){
  const float* x      = (const float*)d_in[0];
  const float* W_real = (const float*)d_in[1];
  const float* b_real = (const float*)d_in[2];
  // d_in[3] = W_imag, d_in[4] = b_imag : dead (zi never affects zr or y)
  const float* U      = (const float*)d_in[5];
  const float* b_U    = (const float*)d_in[6];
  const float* W_tau  = (const float*)d_in[7];
  const float* b_tau  = (const float*)d_in[8];
  const float* W_out  = (const float*)d_in[9];
  const float* b_out  = (const float*)d_in[10];
  __bf16* uxz = (__bf16*)d_ws;   // T*B*HID bf16, permuted-h layout:
                                 // holds 3.2*(Ux+b), then zr_t (bf16)

  ux_gemm<<<dim3((T_STEPS*BATCH)/64), dim3(256), 0, stream>>>(x, U, b_real, b_U, uxz);
  scan_k <<<dim3(BATCH/32),           dim3(512), 0, stream>>>(W_real, W_tau, b_tau, uxz);
  y_gemm <<<dim3((T_STEPS*BATCH)/64), dim3(256), 0, stream>>>(uxz, W_out, b_out, (float*)d_out);
}

// Round 9
// 961.460 us; speedup vs baseline: 2.5559x; 2.5559x over previous
//
#include <hip/hip_runtime.h>

#define T_STEPS 1024
#define BATCH   256
#define IND     128
#define HID     256
#define OUTD    64

typedef float  f32x4  __attribute__((ext_vector_type(4)));
typedef __bf16 bf16x8 __attribute__((ext_vector_type(8)));
typedef int    i32x8  __attribute__((ext_vector_type(8)));

__device__ __forceinline__ bf16x8 cvt8(float4 a, float4 b){
  bf16x8 v;
  v[0]=(__bf16)a.x; v[1]=(__bf16)a.y; v[2]=(__bf16)a.z; v[3]=(__bf16)a.w;
  v[4]=(__bf16)b.x; v[5]=(__bf16)b.y; v[6]=(__bf16)b.z; v[7]=(__bf16)b.w;
  return v;
}
// pack 4 f32 -> 4 fp8(e4m3) bytes in one dword
__device__ __forceinline__ int pk_fp8x4(float a, float b, float c, float d){
  int r = __builtin_amdgcn_cvt_pk_fp8_f32(a, b, 0, false);
  r     = __builtin_amdgcn_cvt_pk_fp8_f32(c, d, r, true);
  return r;
}
__device__ __forceinline__ float bflo(unsigned u){ return __builtin_bit_cast(float, u<<16); }
__device__ __forceinline__ float bfhi(unsigned u){ return __builtin_bit_cast(float, u & 0xffff0000u); }

// permuted h-index in the uxz workspace: h = w*32+nt*16+kg*4+j -> ph = w*32+kg*8+nt*4+j
// (scan lane (w,kg,ln15) owns ph = w*32+kg*8 .. +7 : ONE contiguous 16B slot)

// ---------------------------------------------------------------------------
// Kernel 1: uxz'[t,b,ph] = bf16( 3.2*(x@U^T + b_U + b_real) )
// (3.2 = 32*0.1: scan's W_real is stored fp8(3.2*W), and aR_total/32 recovers
//  0.1*(W.tanh + Ux + b); swapped MFMA -> packed b64 permuted stores)
// ---------------------------------------------------------------------------
__global__ __launch_bounds__(256) void ux_gemm(const float* __restrict__ x,
                                               const float* __restrict__ U,
                                               const float* __restrict__ b_real,
                                               const float* __restrict__ b_U,
                                               __bf16* __restrict__ uxz){
  __shared__ bf16x8 Ub[4096];   // [16 nt][4 c][64 lanes] A-frags, 64 KB
  const int tid = threadIdx.x;
  for(int s = tid; s < 4096; s += 256){
    const int l = s & 63, c = (s>>6)&3, nt = s>>8;
    const int n = nt*16 + (l&15), k = c*32 + ((l>>4)<<3);
    const float4* p = (const float4*)(U + n*IND + k);
    Ub[s] = cvt8(p[0], p[1]);
  }
  __syncthreads();
  const int wave = tid>>6, lane = tid&63, ln15 = lane&15, kg = lane>>4;
  const int row0 = blockIdx.x*64 + wave*16;
  const int grow = row0 + ln15;
  bf16x8 xf[4];
  #pragma unroll
  for(int c=0;c<4;c++){
    const float4* p = (const float4*)(x + (size_t)grow*IND + c*32 + (kg<<3));
    xf[c] = cvt8(p[0], p[1]);
  }
  #pragma unroll
  for(int nt=0;nt<16;nt++){
    f32x4 acc = {0.f,0.f,0.f,0.f};
    #pragma unroll
    for(int c=0;c<4;c++)
      acc = __builtin_amdgcn_mfma_f32_16x16x32_bf16(Ub[(nt*4+c)*64 + lane], xf[c], acc, 0,0,0);
    const int hb = nt*16 + (kg<<2);
    const float4 br = *(const float4*)(b_real + hb);
    const float4 bu = *(const float4*)(b_U + hb);
    const float brv[4] = {br.x,br.y,br.z,br.w};
    const float buv[4] = {bu.x,bu.y,bu.z,bu.w};
    unsigned short hs[4];
    #pragma unroll
    for(int j=0;j<4;j++)
      hs[j] = __builtin_bit_cast(unsigned short, (__bf16)(3.2f*(acc[j] + brv[j] + buv[j])));
    uint2 pk;
    pk.x = (unsigned)hs[0] | ((unsigned)hs[1]<<16);
    pk.y = (unsigned)hs[2] | ((unsigned)hs[3]<<16);
    *(uint2*)(uxz + (size_t)grow*HID + ((nt>>1)<<5) + (kg<<3) + ((nt&1)<<2)) = pk;
  }
}

// ---------------------------------------------------------------------------
// Kernel 2: persistent scan. 16 WGs x 512 thr (8 waves, 2/SIMD). R7 structure,
// with the GEMM inner loop moved to mfma_scale_f32_16x16x128_f8f6f4 (fp8 fmt,
// scale = e8m0 1.0): 8 MFMA/wave/step (was 32), 2-deep chains, no acc-merge.
// k-order safety: A (weights, packed at setup) and B (state, R7 LDS layout)
// use the SAME (dword,byte)->k assignment, so the HW's internal k schedule
// cancels (A.k(q,i,j) == B.k(q,i,j) for any fixed schedule).
// ---------------------------------------------------------------------------
__global__ __launch_bounds__(512,2) void scan_k(
    const float* __restrict__ W_real, const float* __restrict__ W_tau,
    const float* __restrict__ b_tau,  __bf16* __restrict__ uxz){
  __shared__ char lds[16384];   // 2 bufs * (z8 4KB + t8 4KB)
  const int tid = threadIdx.x, w = tid>>6, lane = tid&63;
  const int ln15 = lane&15, kg = lane>>4;
  const float KNEG = -0.09016844f;           // -log2(e)/16
  const float TL2E = 2.88539008f;            // 2*log2(e)
  const int SC1 = 0x7F7F7F7F;                // e8m0 scale = 1.0 (all blocks)

  // A-frags for K=128: wA[nt][kc] = 8 dwords = chunks (4kc..4kc+3) as lo,hi
  // pairs; chunk c covers k = c*32 + kg*8 + {0..7}.
  i32x8 wr8[2][2], wt8[2][2];
  #pragma unroll
  for(int nt=0;nt<2;nt++){
    const int n = w*32 + nt*16 + ln15;
    #pragma unroll
    for(int kc=0;kc<2;kc++){
      i32x8 ar, at;
      #pragma unroll
      for(int cp=0;cp<4;cp++){
        const int k = (kc*4+cp)*32 + (kg<<3);
        const float4 r0 = *(const float4*)(W_real + n*HID + k);
        const float4 r1 = *(const float4*)(W_real + n*HID + k + 4);
        ar[2*cp]   = pk_fp8x4(3.2f*r0.x,3.2f*r0.y,3.2f*r0.z,3.2f*r0.w);
        ar[2*cp+1] = pk_fp8x4(3.2f*r1.x,3.2f*r1.y,3.2f*r1.z,3.2f*r1.w);
        const float4 t0 = *(const float4*)(W_tau + n*HID + k);
        const float4 t1 = *(const float4*)(W_tau + n*HID + k + 4);
        at[2*cp]   = pk_fp8x4(16.f*t0.x,16.f*t0.y,16.f*t0.z,16.f*t0.w);
        at[2*cp+1] = pk_fp8x4(16.f*t1.x,16.f*t1.y,16.f*t1.z,16.f*t1.w);
      }
      wr8[nt][kc] = ar;
      wt8[nt][kc] = at;
    }
  }
  f32x4 bt16[2];
  #pragma unroll
  for(int nt=0;nt<2;nt++){
    const float4 bt = *(const float4*)(b_tau + w*32 + nt*16 + (kg<<2));
    bt16[nt] = (f32x4){16.f*bt.x, 16.f*bt.y, 16.f*bt.z, 16.f*bt.w};
  }

  for(int s = tid; s < 1024; s += 512)
    ((float4*)lds)[s] = float4{0.f,0.f,0.f,0.f};
  __syncthreads();

  // producer write offset (z8 region; t8 = +4096), verified R6/R7:
  // h = w*32+nt*16+kg*4+j -> chunk c=w, frag lane' = (nt*2+(kg>>1))*16+ln15,
  // byte = (w>>1)*1024 + lane'*16 + (w&1)*8 + (kg&1)*4  (+j, contiguous b32)
  int vwZ[2];
  #pragma unroll
  for(int nt=0;nt<2;nt++)
    vwZ[nt] = ((w>>1)<<10) + (((nt*2+(kg>>1))*16 + ln15)<<4) + ((w&1)<<3) + ((kg&1)<<2);

  const int row  = blockIdx.x*16 + ln15;
  const int loff = row*HID + (w<<5) + (kg<<3);   // lane's contiguous 8-elem slot

  float zr[2][4];
  #pragma unroll
  for(int nt=0;nt<2;nt++)
    #pragma unroll
    for(int j=0;j<4;j++) zr[nt][j]=0.f;

  uint4 uxr = *(const uint4*)(uxz + loff);

  auto step = [&](const int BO, const int BN, const int T){
    const int tn = (T < T_STEPS-1) ? T+1 : T;
    const uint4 uxn = *(const uint4*)(uxz + (size_t)tn*(BATCH*HID) + loff);

    f32x4 aT[2], aR[2];
    aT[0] = bt16[0]; aT[1] = bt16[1];
    aR[0] = (f32x4){bflo(uxr.x), bfhi(uxr.x), bflo(uxr.y), bfhi(uxr.y)};
    aR[1] = (f32x4){bflo(uxr.z), bfhi(uxr.z), bflo(uxr.w), bfhi(uxr.w)};

    // B-frags for K=128: kc0 = LDS blocks 0,1 (chunks 0..3); kc1 = blocks 2,3
    const uint4 zp0 = *(const uint4*)(lds + BO + (lane<<4));
    const uint4 zp1 = *(const uint4*)(lds + BO + (lane<<4) + 1024);
    const uint4 zp2 = *(const uint4*)(lds + BO + (lane<<4) + 2048);
    const uint4 zp3 = *(const uint4*)(lds + BO + (lane<<4) + 3072);
    const uint4 tp0 = *(const uint4*)(lds + BO + 4096 + (lane<<4));
    const uint4 tp1 = *(const uint4*)(lds + BO + 4096 + (lane<<4) + 1024);
    const uint4 tp2 = *(const uint4*)(lds + BO + 4096 + (lane<<4) + 2048);
    const uint4 tp3 = *(const uint4*)(lds + BO + 4096 + (lane<<4) + 3072);
    const i32x8 zlo = {(int)zp0.x,(int)zp0.y,(int)zp0.z,(int)zp0.w,
                       (int)zp1.x,(int)zp1.y,(int)zp1.z,(int)zp1.w};
    const i32x8 zhi = {(int)zp2.x,(int)zp2.y,(int)zp2.z,(int)zp2.w,
                       (int)zp3.x,(int)zp3.y,(int)zp3.z,(int)zp3.w};
    const i32x8 tlo = {(int)tp0.x,(int)tp0.y,(int)tp0.z,(int)tp0.w,
                       (int)tp1.x,(int)tp1.y,(int)tp1.z,(int)tp1.w};
    const i32x8 thi = {(int)tp2.x,(int)tp2.y,(int)tp2.z,(int)tp2.w,
                       (int)tp3.x,(int)tp3.y,(int)tp3.z,(int)tp3.w};

    #pragma unroll
    for(int nt=0;nt<2;nt++){
      aT[nt] = __builtin_amdgcn_mfma_scale_f32_16x16x128_f8f6f4(
                 wt8[nt][0], zlo, aT[nt], 0,0, 0,SC1, 0,SC1);
      aT[nt] = __builtin_amdgcn_mfma_scale_f32_16x16x128_f8f6f4(
                 wt8[nt][1], zhi, aT[nt], 0,0, 0,SC1, 0,SC1);
      aR[nt] = __builtin_amdgcn_mfma_scale_f32_16x16x128_f8f6f4(
                 wr8[nt][0], tlo, aR[nt], 0,0, 0,SC1, 0,SC1);
      aR[nt] = __builtin_amdgcn_mfma_scale_f32_16x16x128_f8f6f4(
                 wr8[nt][1], thi, aR[nt], 0,0, 0,SC1, 0,SC1);
    }

    int z8w[2], t8w[2];
    uint4 zst;
    #pragma unroll
    for(int nt=0;nt<2;nt++){
      float znv[4], tvv[4];
      unsigned short zh[4];
      #pragma unroll
      for(int j=0;j<4;j++){
        const float g  = __builtin_amdgcn_exp2f(aT[nt][j]*KNEG);    // e^{-x}
        const float zm = -0.1f*zr[nt][j];
        const float d  = __builtin_fmaf(aR[nt][j], 0.03125f, zm);   // 0.1*pre
        const float s  = zr[nt][j] + d;
        const float zn = __builtin_fmaf(d, g, s);                   // zr + d*(1+g)
        zr[nt][j] = zn;
        znv[j] = zn;
        const float e2 = __builtin_amdgcn_exp2f(zn*TL2E);
        const float r  = __builtin_amdgcn_rcpf(e2 + 1.f);
        tvv[j] = __builtin_fmaf(-2.f, r, 1.f);                      // tanh(zn)
        zh[j]  = __builtin_bit_cast(unsigned short, (__bf16)zn);
      }
      z8w[nt] = pk_fp8x4(znv[0], znv[1], znv[2], znv[3]);
      t8w[nt] = pk_fp8x4(tvv[0], tvv[1], tvv[2], tvv[3]);
      if(nt==0){ zst.x = (unsigned)zh[0] | ((unsigned)zh[1]<<16);
                 zst.y = (unsigned)zh[2] | ((unsigned)zh[3]<<16); }
      else     { zst.z = (unsigned)zh[0] | ((unsigned)zh[1]<<16);
                 zst.w = (unsigned)zh[2] | ((unsigned)zh[3]<<16); }
    }

    #pragma unroll
    for(int nt=0;nt<2;nt++){
      *(int*)(lds + BN + vwZ[nt])        = z8w[nt];
      *(int*)(lds + BN + 4096 + vwZ[nt]) = t8w[nt];
    }
    uxr = uxn;
    __syncthreads();
    *(uint4*)(uxz + (size_t)T*(BATCH*HID) + loff) = zst;   // zr_t for y_gemm
  };

  for(int tt=0; tt<T_STEPS; tt+=2){
    step(0,    8192, tt);
    step(8192, 0,    tt+1);
  }
}

// ---------------------------------------------------------------------------
// Kernel 3: y[m,o] = sum_h zr[m,h] * W_out[o,h] + b_out[o]   (fp32 out)
// zr read from the permuted uxz layout (2xb64 per 32-wide k-chunk).
// ---------------------------------------------------------------------------
__global__ __launch_bounds__(256) void y_gemm(
    const __bf16* __restrict__ zrbuf, const float* __restrict__ W_out,
    const float* __restrict__ b_out, float* __restrict__ y){
  __shared__ bf16x8 Wo[2048];   // [4 nt][8 c][64 lanes], 32 KB
  const int tid = threadIdx.x;
  for(int s=tid; s<2048; s+=256){
    const int l = s&63, c = (s>>6)&7, nt = s>>9;
    const int n = nt*16 + (l&15), k = c*32 + ((l>>4)<<3);
    const float4* p = (const float4*)(W_out + n*HID + k);
    Wo[s] = cvt8(p[0], p[1]);
  }
  __syncthreads();
  const int wave = tid>>6, lane = tid&63, kg = lane>>4;
  const int row0 = blockIdx.x*64 + wave*16;
  const int pA = (((2*kg  )&3)<<3) + ((kg>>1)<<2);
  const int pB = (((2*kg+1)&3)<<3) + ((kg>>1)<<2);
  const __bf16* zb = zrbuf + (size_t)(row0 + (lane&15))*HID;
  bf16x8 af[8];
  #pragma unroll
  for(int c=0;c<8;c++){
    const uint2 lo = *(const uint2*)(zb + c*32 + pA);
    const uint2 hi = *(const uint2*)(zb + c*32 + pB);
    af[c] = __builtin_bit_cast(bf16x8, (uint4){lo.x, lo.y, hi.x, hi.y});
  }
  f32x4 acc[4];
  #pragma unroll
  for(int nt=0;nt<4;nt++) acc[nt] = (f32x4){0,0,0,0};
  #pragma unroll
  for(int nt=0;nt<4;nt++)
    #pragma unroll
    for(int c=0;c<8;c++)
      acc[nt] = __builtin_amdgcn_mfma_f32_16x16x32_bf16(af[c], Wo[(nt*8+c)*64 + lane], acc[nt], 0,0,0);
  const int mb = (lane>>4)<<2, oc = lane&15;
  #pragma unroll
  for(int nt=0;nt<4;nt++){
    const float bo = b_out[nt*16 + oc];
    #pragma unroll
    for(int j=0;j<4;j++)
      y[(size_t)(row0 + mb + j)*OUTD + nt*16 + oc] = acc[nt][j] + bo;
  }
}

extern "C" void kernel_launch(void* const* d_in, const int* in_sizes, int n_in,
                              void* d_out, int out_size, void* d_ws, size_t ws_size,
                              hipStream_t stream){
  const float* x      = (const float*)d_in[0];
  const float* W_real = (const float*)d_in[1];
  const float* b_real = (const float*)d_in[2];
  // d_in[3] = W_imag, d_in[4] = b_imag : dead (zi never affects zr or y)
  const float* U      = (const float*)d_in[5];
  const float* b_U    = (const float*)d_in[6];
  const float* W_tau  = (const float*)d_in[7];
  const float* b_tau  = (const float*)d_in[8];
  const float* W_out  = (const float*)d_in[9];
  const float* b_out  = (const float*)d_in[10];
  __bf16* uxz = (__bf16*)d_ws;   // T*B*HID bf16, permuted-h layout:
                                 // holds 3.2*(Ux+b) then zr_t (bf16)

  ux_gemm<<<dim3((T_STEPS*BATCH)/64), dim3(256), 0, stream>>>(x, U, b_real, b_U, uxz);
  scan_k <<<dim3(BATCH/16),           dim3(512), 0, stream>>>(W_real, W_tau, b_tau, uxz);
  y_gemm <<<dim3((T_STEPS*BATCH)/64), dim3(256), 0, stream>>>(uxz, W_out, b_out, (float*)d_out);
}

// Round 10
// 928.211 us; speedup vs baseline: 2.6474x; 1.0358x over previous
//
#include <hip/hip_runtime.h>

#define T_STEPS 1024
#define BATCH   256
#define IND     128
#define HID     256
#define OUTD    64

typedef float  f32x4  __attribute__((ext_vector_type(4)));
typedef __bf16 bf16x8 __attribute__((ext_vector_type(8)));
typedef int    i32x8  __attribute__((ext_vector_type(8)));

__device__ __forceinline__ bf16x8 cvt8(float4 a, float4 b){
  bf16x8 v;
  v[0]=(__bf16)a.x; v[1]=(__bf16)a.y; v[2]=(__bf16)a.z; v[3]=(__bf16)a.w;
  v[4]=(__bf16)b.x; v[5]=(__bf16)b.y; v[6]=(__bf16)b.z; v[7]=(__bf16)b.w;
  return v;
}
// pack 4 f32 -> 4 fp8(e4m3) bytes in one dword
__device__ __forceinline__ int pk_fp8x4(float a, float b, float c, float d){
  int r = __builtin_amdgcn_cvt_pk_fp8_f32(a, b, 0, false);
  r     = __builtin_amdgcn_cvt_pk_fp8_f32(c, d, r, true);
  return r;
}
__device__ __forceinline__ float bflo(unsigned u){ return __builtin_bit_cast(float, u<<16); }
__device__ __forceinline__ float bfhi(unsigned u){ return __builtin_bit_cast(float, u & 0xffff0000u); }

// permuted h-index in the uxz workspace: h = w*32+nt*16+kg*4+j -> ph = w*32+kg*8+nt*4+j
// (scan lane (w,kg,ln15) owns ph = w*32+kg*8 .. +7 : ONE contiguous 16B slot)

// ---------------------------------------------------------------------------
// Kernel 1: uxz'[t,b,ph] = bf16( 3.2*(x@U^T + b_U + b_real) )
// R10: 256 rows/block (grid 1024), U staged ONCE per block, 4 row-tile loop
// -> U-staging traffic and per-block overhead / 4. Inner math unchanged (R9).
// ---------------------------------------------------------------------------
__global__ __launch_bounds__(256) void ux_gemm(const float* __restrict__ x,
                                               const float* __restrict__ U,
                                               const float* __restrict__ b_real,
                                               const float* __restrict__ b_U,
                                               __bf16* __restrict__ uxz){
  __shared__ bf16x8 Ub[4096];   // [16 nt][4 c][64 lanes] A-frags, 64 KB
  const int tid = threadIdx.x;
  for(int s = tid; s < 4096; s += 256){
    const int l = s & 63, c = (s>>6)&3, nt = s>>8;
    const int n = nt*16 + (l&15), k = c*32 + ((l>>4)<<3);
    const float4* p = (const float4*)(U + n*IND + k);
    Ub[s] = cvt8(p[0], p[1]);
  }
  __syncthreads();
  const int wave = tid>>6, lane = tid&63, ln15 = lane&15, kg = lane>>4;
  #pragma unroll
  for(int rt=0; rt<4; ++rt){
    const int row0 = blockIdx.x*256 + rt*64 + wave*16;
    const int grow = row0 + ln15;
    bf16x8 xf[4];
    #pragma unroll
    for(int c=0;c<4;c++){
      const float4* p = (const float4*)(x + (size_t)grow*IND + c*32 + (kg<<3));
      xf[c] = cvt8(p[0], p[1]);
    }
    #pragma unroll
    for(int nt=0;nt<16;nt++){
      f32x4 acc = {0.f,0.f,0.f,0.f};
      #pragma unroll
      for(int c=0;c<4;c++)
        acc = __builtin_amdgcn_mfma_f32_16x16x32_bf16(Ub[(nt*4+c)*64 + lane], xf[c], acc, 0,0,0);
      const int hb = nt*16 + (kg<<2);
      const float4 br = *(const float4*)(b_real + hb);
      const float4 bu = *(const float4*)(b_U + hb);
      const float brv[4] = {br.x,br.y,br.z,br.w};
      const float buv[4] = {bu.x,bu.y,bu.z,bu.w};
      unsigned short hs[4];
      #pragma unroll
      for(int j=0;j<4;j++)
        hs[j] = __builtin_bit_cast(unsigned short, (__bf16)(3.2f*(acc[j] + brv[j] + buv[j])));
      uint2 pk;
      pk.x = (unsigned)hs[0] | ((unsigned)hs[1]<<16);
      pk.y = (unsigned)hs[2] | ((unsigned)hs[3]<<16);
      *(uint2*)(uxz + (size_t)grow*HID + ((nt>>1)<<5) + (kg<<3) + ((nt&1)<<2)) = pk;
    }
  }
}

// ---------------------------------------------------------------------------
// Kernel 2: persistent scan (UNCHANGED from R9, 786 us known-good).
// 16 WGs x 512 thr (8 waves, 2/SIMD); mfma_scale_f32_16x16x128_f8f6f4
// (fp8 fmt, e8m0 scale=1.0): 8 MFMA/wave/step, 2-deep chains.
// ---------------------------------------------------------------------------
__global__ __launch_bounds__(512,2) void scan_k(
    const float* __restrict__ W_real, const float* __restrict__ W_tau,
    const float* __restrict__ b_tau,  __bf16* __restrict__ uxz){
  __shared__ char lds[16384];   // 2 bufs * (z8 4KB + t8 4KB)
  const int tid = threadIdx.x, w = tid>>6, lane = tid&63;
  const int ln15 = lane&15, kg = lane>>4;
  const float KNEG = -0.09016844f;           // -log2(e)/16
  const float TL2E = 2.88539008f;            // 2*log2(e)
  const int SC1 = 0x7F7F7F7F;                // e8m0 scale = 1.0 (all blocks)

  i32x8 wr8[2][2], wt8[2][2];
  #pragma unroll
  for(int nt=0;nt<2;nt++){
    const int n = w*32 + nt*16 + ln15;
    #pragma unroll
    for(int kc=0;kc<2;kc++){
      i32x8 ar, at;
      #pragma unroll
      for(int cp=0;cp<4;cp++){
        const int k = (kc*4+cp)*32 + (kg<<3);
        const float4 r0 = *(const float4*)(W_real + n*HID + k);
        const float4 r1 = *(const float4*)(W_real + n*HID + k + 4);
        ar[2*cp]   = pk_fp8x4(3.2f*r0.x,3.2f*r0.y,3.2f*r0.z,3.2f*r0.w);
        ar[2*cp+1] = pk_fp8x4(3.2f*r1.x,3.2f*r1.y,3.2f*r1.z,3.2f*r1.w);
        const float4 t0 = *(const float4*)(W_tau + n*HID + k);
        const float4 t1 = *(const float4*)(W_tau + n*HID + k + 4);
        at[2*cp]   = pk_fp8x4(16.f*t0.x,16.f*t0.y,16.f*t0.z,16.f*t0.w);
        at[2*cp+1] = pk_fp8x4(16.f*t1.x,16.f*t1.y,16.f*t1.z,16.f*t1.w);
      }
      wr8[nt][kc] = ar;
      wt8[nt][kc] = at;
    }
  }
  f32x4 bt16[2];
  #pragma unroll
  for(int nt=0;nt<2;nt++){
    const float4 bt = *(const float4*)(b_tau + w*32 + nt*16 + (kg<<2));
    bt16[nt] = (f32x4){16.f*bt.x, 16.f*bt.y, 16.f*bt.z, 16.f*bt.w};
  }

  for(int s = tid; s < 1024; s += 512)
    ((float4*)lds)[s] = float4{0.f,0.f,0.f,0.f};
  __syncthreads();

  int vwZ[2];
  #pragma unroll
  for(int nt=0;nt<2;nt++)
    vwZ[nt] = ((w>>1)<<10) + (((nt*2+(kg>>1))*16 + ln15)<<4) + ((w&1)<<3) + ((kg&1)<<2);

  const int row  = blockIdx.x*16 + ln15;
  const int loff = row*HID + (w<<5) + (kg<<3);   // lane's contiguous 8-elem slot

  float zr[2][4];
  #pragma unroll
  for(int nt=0;nt<2;nt++)
    #pragma unroll
    for(int j=0;j<4;j++) zr[nt][j]=0.f;

  uint4 uxr = *(const uint4*)(uxz + loff);

  auto step = [&](const int BO, const int BN, const int T){
    const int tn = (T < T_STEPS-1) ? T+1 : T;
    const uint4 uxn = *(const uint4*)(uxz + (size_t)tn*(BATCH*HID) + loff);

    f32x4 aT[2], aR[2];
    aT[0] = bt16[0]; aT[1] = bt16[1];
    aR[0] = (f32x4){bflo(uxr.x), bfhi(uxr.x), bflo(uxr.y), bfhi(uxr.y)};
    aR[1] = (f32x4){bflo(uxr.z), bfhi(uxr.z), bflo(uxr.w), bfhi(uxr.w)};

    const uint4 zp0 = *(const uint4*)(lds + BO + (lane<<4));
    const uint4 zp1 = *(const uint4*)(lds + BO + (lane<<4) + 1024);
    const uint4 zp2 = *(const uint4*)(lds + BO + (lane<<4) + 2048);
    const uint4 zp3 = *(const uint4*)(lds + BO + (lane<<4) + 3072);
    const uint4 tp0 = *(const uint4*)(lds + BO + 4096 + (lane<<4));
    const uint4 tp1 = *(const uint4*)(lds + BO + 4096 + (lane<<4) + 1024);
    const uint4 tp2 = *(const uint4*)(lds + BO + 4096 + (lane<<4) + 2048);
    const uint4 tp3 = *(const uint4*)(lds + BO + 4096 + (lane<<4) + 3072);
    const i32x8 zlo = {(int)zp0.x,(int)zp0.y,(int)zp0.z,(int)zp0.w,
                       (int)zp1.x,(int)zp1.y,(int)zp1.z,(int)zp1.w};
    const i32x8 zhi = {(int)zp2.x,(int)zp2.y,(int)zp2.z,(int)zp2.w,
                       (int)zp3.x,(int)zp3.y,(int)zp3.z,(int)zp3.w};
    const i32x8 tlo = {(int)tp0.x,(int)tp0.y,(int)tp0.z,(int)tp0.w,
                       (int)tp1.x,(int)tp1.y,(int)tp1.z,(int)tp1.w};
    const i32x8 thi = {(int)tp2.x,(int)tp2.y,(int)tp2.z,(int)tp2.w,
                       (int)tp3.x,(int)tp3.y,(int)tp3.z,(int)tp3.w};

    #pragma unroll
    for(int nt=0;nt<2;nt++){
      aT[nt] = __builtin_amdgcn_mfma_scale_f32_16x16x128_f8f6f4(
                 wt8[nt][0], zlo, aT[nt], 0,0, 0,SC1, 0,SC1);
      aT[nt] = __builtin_amdgcn_mfma_scale_f32_16x16x128_f8f6f4(
                 wt8[nt][1], zhi, aT[nt], 0,0, 0,SC1, 0,SC1);
      aR[nt] = __builtin_amdgcn_mfma_scale_f32_16x16x128_f8f6f4(
                 wr8[nt][0], tlo, aR[nt], 0,0, 0,SC1, 0,SC1);
      aR[nt] = __builtin_amdgcn_mfma_scale_f32_16x16x128_f8f6f4(
                 wr8[nt][1], thi, aR[nt], 0,0, 0,SC1, 0,SC1);
    }

    int z8w[2], t8w[2];
    uint4 zst;
    #pragma unroll
    for(int nt=0;nt<2;nt++){
      float znv[4], tvv[4];
      unsigned short zh[4];
      #pragma unroll
      for(int j=0;j<4;j++){
        const float g  = __builtin_amdgcn_exp2f(aT[nt][j]*KNEG);    // e^{-x}
        const float zm = -0.1f*zr[nt][j];
        const float d  = __builtin_fmaf(aR[nt][j], 0.03125f, zm);   // 0.1*pre
        const float s  = zr[nt][j] + d;
        const float zn = __builtin_fmaf(d, g, s);                   // zr + d*(1+g)
        zr[nt][j] = zn;
        znv[j] = zn;
        const float e2 = __builtin_amdgcn_exp2f(zn*TL2E);
        const float r  = __builtin_amdgcn_rcpf(e2 + 1.f);
        tvv[j] = __builtin_fmaf(-2.f, r, 1.f);                      // tanh(zn)
        zh[j]  = __builtin_bit_cast(unsigned short, (__bf16)zn);
      }
      z8w[nt] = pk_fp8x4(znv[0], znv[1], znv[2], znv[3]);
      t8w[nt] = pk_fp8x4(tvv[0], tvv[1], tvv[2], tvv[3]);
      if(nt==0){ zst.x = (unsigned)zh[0] | ((unsigned)zh[1]<<16);
                 zst.y = (unsigned)zh[2] | ((unsigned)zh[3]<<16); }
      else     { zst.z = (unsigned)zh[0] | ((unsigned)zh[1]<<16);
                 zst.w = (unsigned)zh[2] | ((unsigned)zh[3]<<16); }
    }

    #pragma unroll
    for(int nt=0;nt<2;nt++){
      *(int*)(lds + BN + vwZ[nt])        = z8w[nt];
      *(int*)(lds + BN + 4096 + vwZ[nt]) = t8w[nt];
    }
    uxr = uxn;
    __syncthreads();
    *(uint4*)(uxz + (size_t)T*(BATCH*HID) + loff) = zst;   // zr_t for y_gemm
  };

  for(int tt=0; tt<T_STEPS; tt+=2){
    step(0,    8192, tt);
    step(8192, 0,    tt+1);
  }
}

// ---------------------------------------------------------------------------
// Kernel 3: y[m,o] = sum_h zr[m,h] * W_out[o,h] + b_out[o]   (fp32 out)
// R10: 256 rows/block (grid 1024), W_out staged ONCE, 4 row-tile loop.
// zr read from the permuted uxz layout (2xb64 per 32-wide k-chunk).
// ---------------------------------------------------------------------------
__global__ __launch_bounds__(256) void y_gemm(
    const __bf16* __restrict__ zrbuf, const float* __restrict__ W_out,
    const float* __restrict__ b_out, float* __restrict__ y){
  __shared__ bf16x8 Wo[2048];   // [4 nt][8 c][64 lanes], 32 KB
  const int tid = threadIdx.x;
  for(int s=tid; s<2048; s+=256){
    const int l = s&63, c = (s>>6)&7, nt = s>>9;
    const int n = nt*16 + (l&15), k = c*32 + ((l>>4)<<3);
    const float4* p = (const float4*)(W_out + n*HID + k);
    Wo[s] = cvt8(p[0], p[1]);
  }
  __syncthreads();
  const int wave = tid>>6, lane = tid&63, kg = lane>>4;
  const int pA = (((2*kg  )&3)<<3) + ((kg>>1)<<2);
  const int pB = (((2*kg+1)&3)<<3) + ((kg>>1)<<2);
  const int mb = (lane>>4)<<2, oc = lane&15;
  float bov[4];
  #pragma unroll
  for(int nt=0;nt<4;nt++) bov[nt] = b_out[nt*16 + oc];
  #pragma unroll
  for(int rt=0; rt<4; ++rt){
    const int row0 = blockIdx.x*256 + rt*64 + wave*16;
    const __bf16* zb = zrbuf + (size_t)(row0 + (lane&15))*HID;
    bf16x8 af[8];
    #pragma unroll
    for(int c=0;c<8;c++){
      const uint2 lo = *(const uint2*)(zb + c*32 + pA);
      const uint2 hi = *(const uint2*)(zb + c*32 + pB);
      af[c] = __builtin_bit_cast(bf16x8, (uint4){lo.x, lo.y, hi.x, hi.y});
    }
    f32x4 acc[4];
    #pragma unroll
    for(int nt=0;nt<4;nt++) acc[nt] = (f32x4){0,0,0,0};
    #pragma unroll
    for(int nt=0;nt<4;nt++)
      #pragma unroll
      for(int c=0;c<8;c++)
        acc[nt] = __builtin_amdgcn_mfma_f32_16x16x32_bf16(af[c], Wo[(nt*8+c)*64 + lane], acc[nt], 0,0,0);
    #pragma unroll
    for(int nt=0;nt<4;nt++){
      #pragma unroll
      for(int j=0;j<4;j++)
        y[(size_t)(row0 + mb + j)*OUTD + nt*16 + oc] = acc[nt][j] + bov[nt];
    }
  }
}

extern "C" void kernel_launch(void* const* d_in, const int* in_sizes, int n_in,
                              void* d_out, int out_size, void* d_ws, size_t ws_size,
                              hipStream_t stream){
  const float* x      = (const float*)d_in[0];
  const float* W_real = (const float*)d_in[1];
  const float* b_real = (const float*)d_in[2];
  // d_in[3] = W_imag, d_in[4] = b_imag : dead (zi never affects zr or y)
  const float* U      = (const float*)d_in[5];
  const float* b_U    = (const float*)d_in[6];
  const float* W_tau  = (const float*)d_in[7];
  const float* b_tau  = (const float*)d_in[8];
  const float* W_out  = (const float*)d_in[9];
  const float* b_out  = (const float*)d_in[10];
  __bf16* uxz = (__bf16*)d_ws;   // T*B*HID bf16, permuted-h layout:
                                 // holds 3.2*(Ux+b) then zr_t (bf16)

  ux_gemm<<<dim3((T_STEPS*BATCH)/256), dim3(256), 0, stream>>>(x, U, b_real, b_U, uxz);
  scan_k <<<dim3(BATCH/16),            dim3(512), 0, stream>>>(W_real, W_tau, b_tau, uxz);
  y_gemm <<<dim3((T_STEPS*BATCH)/256), dim3(256), 0, stream>>>(uxz, W_out, b_out, (float*)d_out);
}